// Round 5
// baseline (257.913 us; speedup 1.0000x reference)
//
#include <hip/hip_runtime.h>

// Problem constants (B=8, A=3, H=200, W=304)
#define HWSZ 60800      // H*W
#define NA 3
#define NTOT 182400     // A*H*W
#define KSEL 2000
#define CANDCAP 8192
#define NBATCH 8
#define GSPLIT_F 32     // fused-front partitions (256 blocks total -> all co-resident)
#define LOG_MAX_F 4.135166556742356f   // log(1000/16) rounded to fp32

// ---- workspace layout (bytes) ----
#define OFF_H1    0          // 8*2048*4 = 65536
#define OFF_CCNT  65536      // 8*4 = 32
#define OFF_DONE  65568      // 8*4 = 32 (hist last-block counters)
#define OFF_RDY   65600      // 8*4 = 32 (selinfo-ready flags)
#define OFF_DONE2 65632      // 8*4 = 32 (gather-done counters)
#define ZR_BYTES  65664      // zeroes H1 + CCNT + DONE + RDY + DONE2
#define OFF_SEL   65664      // 8*16 = 128 (16B aligned)
#define OFF_BOX   65792      // 8*2000*16 = 256000 (16B aligned)
#define OFF_VALID 321792     // 8*2000*4 = 64000
#define OFF_SUP   385792     // 8*2000*32*8 = 4096000 (16B aligned)
#define OFF_CAND  385792     // overlay on sup (lifetime: gather->rank in K1; sup written in K2)
#define OFF_SUPT  4481792    // transposed 64x64 diag blocks: 8*32*64*8 = 131072

__device__ __forceinline__ unsigned int xform(float f) {
    unsigned int b = __float_as_uint(f);
    return b ^ ((unsigned int)((int)b >> 31) | 0x80000000u);  // monotonic float->uint
}

// LDS-only barrier: does NOT drain vmcnt, so prefetched global loads (private
// VGPR dests) stay in flight across it. LDS ordering via lgkmcnt(0).
__device__ __forceinline__ void bar_lds() {
    asm volatile("s_waitcnt lgkmcnt(0)" ::: "memory");
    __builtin_amdgcn_s_barrier();
}

// ======== Kernel 1 (fused front): hist -> scan -> gather -> rank+decode ========
// Grid (GSPLIT_F, NBATCH) = 256 blocks of 256 threads, guaranteed co-resident
// (1024 waves vs 8192 capacity; 33 KB LDS/block). Intra-kernel phases are
// ordered with agent-scope done-counters + acquire spins (pattern validated by
// the hist last-block scan in prior rounds, absmax 0.0).
__global__ __launch_bounds__(256) void k_front(
        const float* __restrict__ cls,
        unsigned int* __restrict__ hist1,
        unsigned int* __restrict__ done,
        unsigned int* __restrict__ done2,
        unsigned int* __restrict__ ready,
        uint4* __restrict__ selinfo,
        unsigned long long* __restrict__ cand,
        unsigned int* __restrict__ ccnt,
        const float* __restrict__ regs,
        const float* __restrict__ anchors,
        const int* __restrict__ img_h,
        const int* __restrict__ img_w,
        float* __restrict__ out_scores,
        float4* __restrict__ boxes_ws,
        unsigned int* __restrict__ valid_ws) {
    int b = blockIdx.y, part = blockIdx.x, tid = threadIdx.x;
    __shared__ unsigned int h[2048];
    __shared__ unsigned int sa[2048], sb[2048];
    __shared__ unsigned long long lbuf[1024];
    __shared__ unsigned int cntsh[4][64];
    __shared__ unsigned int lcnt, gbase, slast;

    // ---- phase 1: per-block LDS histogram of top-11 key bits ----
    for (int i = tid; i < 2048; i += 256) h[i] = 0u;
    __syncthreads();
    const float4* base4 = (const float4*)(cls + (size_t)b * NTOT);
    const int n4 = NTOT / 4;
    int per = (n4 + GSPLIT_F - 1) / GSPLIT_F;
    int lo = part * per, hi = lo + per;
    if (hi > n4) hi = n4;
    for (int i = lo + tid; i < hi; i += 256) {
        float4 v = base4[i];
        atomicAdd(&h[xform(v.x) >> 21], 1u);
        atomicAdd(&h[xform(v.y) >> 21], 1u);
        atomicAdd(&h[xform(v.z) >> 21], 1u);
        atomicAdd(&h[xform(v.w) >> 21], 1u);
    }
    __syncthreads();
    unsigned int* gh = hist1 + b * 2048;
    for (int i = tid; i < 2048; i += 256)
        if (h[i]) atomicAdd(&gh[i], h[i]);
    __syncthreads();                 // block's global atomics drained (waitcnt before barrier)
    if (tid == 0) {
        __threadfence();             // release our hist contributions
        unsigned int old = __hip_atomic_fetch_add(&done[b], 1u, __ATOMIC_ACQ_REL,
                                                  __HIP_MEMORY_SCOPE_AGENT);
        slast = (old == GSPLIT_F - 1) ? 1u : 0u;
    }
    __syncthreads();

    // ---- phase 2: last block per batch does the 2048-bin suffix scan ----
    if (slast) {
        #pragma unroll
        for (int k = 0; k < 8; ++k) {
            int i = tid + k * 256;
            sa[i] = __hip_atomic_load(&gh[i], __ATOMIC_RELAXED, __HIP_MEMORY_SCOPE_AGENT);
        }
        unsigned int* src = sa; unsigned int* dst = sb;
        for (int d = 1; d < 2048; d <<= 1) {
            __syncthreads();
            #pragma unroll
            for (int k = 0; k < 8; ++k) {
                int i = tid + k * 256;
                dst[i] = src[i] + ((i + d < 2048) ? src[i + d] : 0u);
            }
            unsigned int* t = src; src = dst; dst = t;
        }
        __syncthreads();
        #pragma unroll
        for (int k = 0; k < 8; ++k) {
            int i = tid + k * 256;
            unsigned int c = src[i];
            unsigned int cn = (i < 2047) ? src[i + 1] : 0u;
            if (c >= KSEL && cn < KSEL)
                selinfo[b] = make_uint4((unsigned int)i, cn, KSEL - cn, 0u);
        }
        __syncthreads();             // selinfo store issued & in this CU's L2
        if (tid == 0)
            __hip_atomic_store(&ready[b], 1u, __ATOMIC_RELEASE, __HIP_MEMORY_SCOPE_AGENT);
    }

    // ---- phase 3: wait for selinfo, then gather candidates from own (L1-hot) partition ----
    if (tid == 0) {
        while (__hip_atomic_load(&ready[b], __ATOMIC_ACQUIRE, __HIP_MEMORY_SCOPE_AGENT) == 0u)
            __builtin_amdgcn_s_sleep(2);
        lcnt = 0u;
    }
    __syncthreads();
    unsigned int bin = selinfo[b].x;
    for (int i = lo + tid; i < hi; i += 256) {
        float4 v = base4[i];
        float vals[4] = {v.x, v.y, v.z, v.w};
        int idx0 = i * 4;
        #pragma unroll
        for (int q = 0; q < 4; ++q) {
            unsigned int u = xform(vals[q]);
            if ((u >> 21) >= bin) {
                int idx = idx0 + q;
                int a = idx / HWSZ;
                int hw = idx - a * HWSZ;
                unsigned int n = (unsigned int)(hw * NA + a);
                unsigned int pos = atomicAdd(&lcnt, 1u);
                if (pos < 1024u)
                    lbuf[pos] = ((unsigned long long)u << 32) | (unsigned long long)(~n);
            }
        }
    }
    __syncthreads();
    if (tid == 0) {
        unsigned int c = lcnt < 1024u ? lcnt : 1024u;
        gbase = atomicAdd(&ccnt[b], c);
    }
    __syncthreads();
    {
        unsigned int c = lcnt < 1024u ? lcnt : 1024u;
        unsigned int gb = gbase;
        for (unsigned int i = tid; i < c; i += 256) {
            unsigned int p_ = gb + i;
            if (p_ < CANDCAP) cand[(size_t)b * CANDCAP + p_] = lbuf[i];
        }
    }
    // ---- all-gathers-done barrier (per batch) ----
    __syncthreads();                 // cand stores drained before fence
    if (tid == 0) {
        __threadfence();
        __hip_atomic_fetch_add(&done2[b], 1u, __ATOMIC_ACQ_REL, __HIP_MEMORY_SCOPE_AGENT);
        while (__hip_atomic_load(&done2[b], __ATOMIC_ACQUIRE, __HIP_MEMORY_SCOPE_AGENT)
               < (unsigned int)GSPLIT_F)
            __builtin_amdgcn_s_sleep(2);
    }
    __syncthreads();

    // ---- phase 4: rank-by-count (4 threads/key) + box decode; chunks strided by 32 ----
    unsigned int sc = ccnt[b];
    if (sc > CANDCAP) sc = CANDCAP;
    int ki = tid & 63;         // key slot within chunk (== lane)
    int q = tid >> 6;          // column-quarter 0..3 (== wave id)
    int lane = tid & 63;
    const unsigned long long* sb_ = cand + (size_t)b * CANDCAP;
    // quarter column range [qlo, qhi); qs is a multiple of 64 with 4*qs >= sc
    unsigned int qs = ((sc + 255u) >> 8) << 6;
    unsigned int qlo = (unsigned int)q * qs;
    unsigned int qhi = qlo + qs;
    if (qhi > sc) qhi = sc;

    int hv = img_h[0];
    int wv = img_w[0];
    float himg = (hv > 0 && hv < 100000) ? (float)hv : __int_as_float(hv);
    float wimg = (wv > 0 && wv < 100000) ? (float)wv : __int_as_float(wv);

    for (unsigned int ch = (unsigned int)part; ch * 64u < sc; ch += GSPLIT_F) {
        unsigned int kbase = ch * 64u;
        unsigned int r = kbase + (unsigned int)ki;
        unsigned long long mykey = (r < sc) ? sb_[r] : 0ULL;
        unsigned int cnt = 0u;
        for (unsigned int base = qlo; base < qhi; base += 64) {
            unsigned long long kj = 0ULL;   // 0 > mykey is false for any real key
            if (base + (unsigned int)lane < qhi) kj = sb_[base + lane];
            unsigned int klo = (unsigned int)kj;
            unsigned int khi = (unsigned int)(kj >> 32);
            #pragma unroll
            for (int t = 0; t < 64; ++t) {
                unsigned int lo_ = (unsigned int)__builtin_amdgcn_readlane((int)klo, t);
                unsigned int hi_ = (unsigned int)__builtin_amdgcn_readlane((int)khi, t);
                unsigned long long kt = ((unsigned long long)hi_ << 32) | (unsigned long long)lo_;
                cnt += (kt > mykey) ? 1u : 0u;
            }
        }
        __syncthreads();   // WAR: previous chunk's cntsh readers done
        cntsh[q][ki] = cnt;
        __syncthreads();
        if (tid < 64) {
            unsigned int rank = cntsh[0][ki] + cntsh[1][ki] + cntsh[2][ki] + cntsh[3][ki];
            if (r < sc && rank < KSEL) {
                unsigned int u = (unsigned int)(mykey >> 32);
                unsigned int n = ~((unsigned int)mykey);
                unsigned int bits = (u & 0x80000000u) ? (u & 0x7FFFFFFFu) : ~u;
                float score = __uint_as_float(bits);
                int a = (int)(n % NA);
                int hw = (int)(n / NA);
                const float* rp = regs + ((size_t)b * (4 * NA) + 4 * a) * HWSZ + hw;
                float dx = rp[0 * HWSZ];
                float dy = rp[1 * HWSZ];
                float dh = rp[2 * HWSZ];
                float dw = rp[3 * HWSZ];
                const float* ap = anchors + ((size_t)b * NTOT + n) * 4;
                float ax1 = ap[0], ay1 = ap[1], ax2 = ap[2], ay2 = ap[3];
                float ahh = ay2 - ay1;
                float aww = ax2 - ax1;
                float cx = aww * 0.5f;
                float cy = ahh * 0.5f;
                float px = cx + dx * aww;
                float py = cy + dy * ahh;
                dh = fminf(dh, LOG_MAX_F);
                dw = fminf(dw, LOG_MAX_F);
                float ph = expf(dh) * ahh;
                float pw = expf(dw) * aww;
                float x1 = px - pw * 0.5f;
                float y1 = py - ph * 0.5f;
                float x2 = px + pw * 0.5f;
                float y2 = py + ph * 0.5f;
                float bwv = fminf(fmaxf(x2, 0.f), wimg) - fminf(fmaxf(x1, 0.f), wimg);
                float bhv = fminf(fmaxf(y2, 0.f), himg) - fminf(fmaxf(y1, 0.f), himg);
                unsigned int valid = (bwv >= 16.f && bhv >= 16.f) ? 1u : 0u;
                size_t o = (size_t)b * KSEL + rank;   // output position = rank
                out_scores[o] = score;
                boxes_ws[o] = make_float4(x1, y1, x2, y2);
                valid_ws[o] = valid;
            }
        }
    }
}

// -------- Kernel 2: suppression bitmask matrix (upper triangle) + transposed diag blocks --------
__global__ __launch_bounds__(256) void k_supmat(const float4* __restrict__ boxes_ws,
                                                unsigned long long* __restrict__ sup,
                                                unsigned long long* __restrict__ supT) {
    int ct = blockIdx.x;    // col tile 0..31
    int rt = blockIdx.y;    // row super-tile 0..7 (256 rows each)
    int b  = blockIdx.z;
    // entire tile strictly below diagonal (all j < i): words are never consumed -> skip
    if (ct * 64 + 63 < rt * 256) return;
    int tid = threadIdx.x;
    __shared__ float4 colbox[64];
    int j0 = ct * 64;
    if (tid < 64) {
        int jl = j0 + tid;
        colbox[tid] = (jl < KSEL) ? boxes_ws[(size_t)b * KSEL + jl]
                                  : make_float4(0.f, 0.f, 0.f, 0.f);
    }
    __syncthreads();
    int i = rt * 256 + tid;
    if (i >= KSEL) return;
    float4 bi = boxes_ws[(size_t)b * KSEL + i];
    float area_i = (bi.z - bi.x) * (bi.w - bi.y);
    unsigned long long word = 0ULL;
    #pragma unroll 8
    for (int jj = 0; jj < 64; ++jj) {
        int j = j0 + jj;
        float4 bj = colbox[jj];
        float area_j = (bj.z - bj.x) * (bj.w - bj.y);
        float ix1 = fmaxf(bi.x, bj.x);
        float iy1 = fmaxf(bi.y, bj.y);
        float ix2 = fminf(bi.z, bj.z);
        float iy2 = fminf(bi.w, bj.w);
        float iw = fmaxf(ix2 - ix1, 0.f);
        float ih = fmaxf(iy2 - iy1, 0.f);
        float inter = iw * ih;
        float uni = area_i + area_j - inter;
        float iou = inter / fmaxf(uni, 1e-6f);
        bool s = (j > i) && (j < KSEL) && (iou > 0.7f);
        if (s) word |= (1ULL << jj);
    }
    // store only words on/above the row's diagonal tile — lower-triangle words
    // are never read by k_nms_scan (saves ~half the write traffic)
    if (ct >= (i >> 6))
        sup[((size_t)b * KSEL + i) * 32 + ct] = word;

    // diagonal wave: emit transposed 64x64 block (column masks) for the NMS fixpoint.
    // wave-uniform condition: wave q covers rows rt*256+q*64..+63 == cols of tile ct.
    if (ct == rt * 4 + (tid >> 6)) {
        int lane = tid & 63;
        unsigned long long cm = 0ULL;
        #pragma unroll
        for (int j = 0; j < 64; ++j) {
            unsigned long long t = __ballot((word >> j) & 1ULL);
            if (lane == j) cm = t;
        }
        supT[((size_t)b * 32 + ct) * 64 + lane] = cm;
    }
}

// ---- Kernel 3: word-tile greedy scan — transposed-diag Jacobi fixpoint, lazy accw,
//      depth-4 prefetch with UNCONDITIONAL clamped loads (no select on load results:
//      the vmcnt wait stays at first USE, so loads genuinely overlap processing) ----
// Per-thread invariant: thread holds word-pair {2p, 2p+1}, p = tid&15, for rows
// lr = (tid>>4) + k*16, k=0..3.
//   - rows >= KSEL: clamped to row 1999; garbage never consumed (kws masks bits >= 2000)
//   - dead pairs (2p+1 < w, lower triangle): remapped to pair 15 (valid address,
//     coalesces with live readers); garbage never applied (both wd guards fail)
#define LOAD_TILE(wnext, buf)                                                \
    {                                                                        \
        int w_ = (wnext);                                                    \
        _Pragma("unroll")                                                    \
        for (int k = 0; k < 4; ++k) {                                        \
            int lr_ = (tid >> 4) + k * 16;                                   \
            int grow_ = w_ * 64 + lr_;                                       \
            if (grow_ > KSEL - 1) grow_ = KSEL - 1;                          \
            int pp_ = (2 * p + 1 >= w_) ? p : 15;                            \
            buf[k] = srowp[(size_t)grow_ * 16 + pp_];                        \
        }                                                                    \
    }

// One LDS barrier per tile (accw visibility). In-tile suppression solved by
// Jacobi fixpoint on the transposed diag block:
//   keep = cand & ~(sup^T . keep)  — antitone on a strictly-triangular DAG
// => unique fixpoint == exact sequential greedy.
#define PROCESS_TILE(w, buf)                                                 \
    {                                                                        \
        bar_lds();                                                           \
        int w_ = (w);                                                        \
        unsigned long long pend_ =                                           \
            ((unsigned long long)accw[w_ * 2 + 1] << 32)                     \
            | (unsigned long long)accw[w_ * 2];                              \
        unsigned long long cand_ = kws[w_] & ~pend_;                         \
        unsigned int clo_ = __builtin_amdgcn_readfirstlane((unsigned int)cand_);        \
        unsigned int chi_ = __builtin_amdgcn_readfirstlane((unsigned int)(cand_ >> 32));\
        unsigned long long cur_ = ((unsigned long long)chi_ << 32)           \
                                  | (unsigned long long)clo_;                \
        if (cur_) {                                                          \
            unsigned long long cmw_ = colT[w_ * 64 + lane];                  \
            unsigned long long k_ = cur_;                                    \
            for (;;) {                                                       \
                unsigned long long sup_ = __ballot((k_ & cmw_) != 0ULL);     \
                unsigned long long k2_ = cur_ & ~sup_;                       \
                if (k2_ == k_) break;                                        \
                k_ = k2_;                                                    \
            }                                                                \
            cur_ = k_;                                                       \
            if (tid == 0) fin[w_] = cur_;                                    \
            unsigned long long v0_ = 0ULL, v1_ = 0ULL;                       \
            _Pragma("unroll")                                                \
            for (int k = 0; k < 4; ++k) {                                    \
                int lr_ = (tid >> 4) + k * 16;                               \
                if ((cur_ >> lr_) & 1ULL) { v0_ |= buf[k].x; v1_ |= buf[k].y; } \
            }                                                                \
            v0_ |= __shfl_xor(v0_, 16, 64); v0_ |= __shfl_xor(v0_, 32, 64);  \
            v1_ |= __shfl_xor(v1_, 16, 64); v1_ |= __shfl_xor(v1_, 32, 64);  \
            if (lane < 16) {                                                 \
                int wd0_ = 2 * p;                                            \
                if (wd0_ > w_ && v0_) {                                      \
                    atomicOr(&accw[wd0_ * 2], (unsigned int)v0_);            \
                    atomicOr(&accw[wd0_ * 2 + 1], (unsigned int)(v0_ >> 32));\
                }                                                            \
                if (wd0_ + 1 > w_ && v1_) {                                  \
                    atomicOr(&accw[wd0_ * 2 + 2], (unsigned int)v1_);        \
                    atomicOr(&accw[wd0_ * 2 + 3], (unsigned int)(v1_ >> 32));\
                }                                                            \
            }                                                                \
        } else if (tid == 0) {                                               \
            fin[w_] = 0ULL;                                                  \
        }                                                                    \
    }

__global__ __launch_bounds__(256) void k_nms_scan(const unsigned long long* __restrict__ sup,
                                                  const unsigned long long* __restrict__ supT,
                                                  const unsigned int* __restrict__ valid_ws,
                                                  const float4* __restrict__ boxes_ws,
                                                  float* __restrict__ out_boxes,
                                                  float* __restrict__ out_keep) {
    int b = blockIdx.x;
    int tid = threadIdx.x;
    int lane = tid & 63;
    int p = tid & 15;                            // word-pair index
    __shared__ unsigned long long kws[32];       // initial validity words
    __shared__ unsigned long long fin[32];       // final keep words
    __shared__ unsigned int accw[64];            // lazy suppression accumulator (monotone)
    __shared__ unsigned long long colT[32 * 64]; // transposed diag blocks (16 KB)
    const ulonglong2* srowp = (const ulonglong2*)(sup + (size_t)b * KSEL * 32);

    // preload all transposed diag columns (read-only afterwards)
    {
        const unsigned long long* stb = supT + (size_t)b * 2048;
        #pragma unroll
        for (int k = 0; k < 8; ++k) {
            int i = tid + k * 256;
            colT[i] = stb[i];
        }
    }

    if (tid < 32) {
        unsigned long long kw = 0ULL;
        const uint4* vv = (const uint4*)(valid_ws + (size_t)b * KSEL);
        #pragma unroll 4
        for (int q = 0; q < 16; ++q) {
            uint4 x = vv[tid * 16 + q];   // tid=31,q>=4 reads past 2000 — bits masked below
            int base = q * 4;
            if (x.x) kw |= 1ULL << (base + 0);
            if (x.y) kw |= 1ULL << (base + 1);
            if (x.z) kw |= 1ULL << (base + 2);
            if (x.w) kw |= 1ULL << (base + 3);
        }
        if (tid == 31) kw &= 0xFFFFULL;   // rows 2000..2047 invalid
        kws[tid] = kw;
    }
    if (tid < 64) accw[tid] = 0u;

    // depth-4 prefetch rotation: cover ~3 process-steps of latency
    ulonglong2 A[4], B[4], C[4], D[4];
    LOAD_TILE(0, A);
    LOAD_TILE(1, B);
    LOAD_TILE(2, C);
    LOAD_TILE(3, D);

    for (int t = 0; t < 8; ++t) {
        int w = 4 * t;
        PROCESS_TILE(w, A);
        if (w + 4 < 32) LOAD_TILE(w + 4, A);   // stays in flight across bar_lds
        PROCESS_TILE(w + 1, B);
        if (w + 5 < 32) LOAD_TILE(w + 5, B);
        PROCESS_TILE(w + 2, C);
        if (w + 6 < 32) LOAD_TILE(w + 6, C);
        PROCESS_TILE(w + 3, D);
        if (w + 7 < 32) LOAD_TILE(w + 7, D);
    }
    bar_lds();

    float4* ob4 = (float4*)out_boxes;
    for (int r = tid; r < KSEL; r += 256) {
        float kf = (float)((fin[r >> 6] >> (r & 63)) & 1ULL);
        size_t o = (size_t)b * KSEL + r;
        out_keep[o] = kf;
        float4 bx = boxes_ws[o];
        ob4[o] = make_float4(bx.x * kf, bx.y * kf, bx.z * kf, bx.w * kf);
    }
}

extern "C" void kernel_launch(void* const* d_in, const int* in_sizes, int n_in,
                              void* d_out, int out_size, void* d_ws, size_t ws_size,
                              hipStream_t stream) {
    const float* cls     = (const float*)d_in[0];
    const float* regs    = (const float*)d_in[1];
    const float* anchors = (const float*)d_in[2];
    const int*   img_h   = (const int*)d_in[3];
    const int*   img_w   = (const int*)d_in[4];

    float* out = (float*)d_out;
    float* out_boxes  = out;            // 8*2000*4
    float* out_scores = out + 64000;    // 8*2000
    float* out_keep   = out + 80000;    // 8*2000

    char* ws = (char*)d_ws;
    unsigned int* hist1      = (unsigned int*)(ws + OFF_H1);
    unsigned int* ccnt       = (unsigned int*)(ws + OFF_CCNT);
    unsigned int* done       = (unsigned int*)(ws + OFF_DONE);
    unsigned int* ready      = (unsigned int*)(ws + OFF_RDY);
    unsigned int* done2      = (unsigned int*)(ws + OFF_DONE2);
    uint4* selinfo           = (uint4*)(ws + OFF_SEL);
    float4* boxes_ws         = (float4*)(ws + OFF_BOX);
    unsigned int* valid_ws   = (unsigned int*)(ws + OFF_VALID);
    unsigned long long* sup  = (unsigned long long*)(ws + OFF_SUP);
    unsigned long long* cand = (unsigned long long*)(ws + OFF_CAND);
    unsigned long long* supT = (unsigned long long*)(ws + OFF_SUPT);

    hipMemsetAsync(ws, 0, ZR_BYTES, stream);
    k_front<<<dim3(GSPLIT_F, NBATCH), 256, 0, stream>>>(cls, hist1, done, done2, ready,
                                                        selinfo, cand, ccnt, regs, anchors,
                                                        img_h, img_w, out_scores,
                                                        boxes_ws, valid_ws);
    k_supmat<<<dim3(32, 8, NBATCH), 256, 0, stream>>>(boxes_ws, sup, supT);
    k_nms_scan<<<NBATCH, 256, 0, stream>>>(sup, supT, valid_ws, boxes_ws, out_boxes, out_keep);
}

// Round 6
// 199.197 us; speedup vs baseline: 1.2948x; 1.2948x over previous
//
#include <hip/hip_runtime.h>

// Problem constants (B=8, A=3, H=200, W=304)
#define HWSZ 60800      // H*W
#define NA 3
#define NTOT 182400     // A*H*W
#define KSEL 2000
#define CANDCAP 8192
#define NBATCH 8
#define GSPLIT 128
#define LOG_MAX_F 4.135166556742356f   // log(1000/16) rounded to fp32

// ---- workspace layout (bytes) ----
#define OFF_H1    0          // 8*2048*4 = 65536
#define OFF_CCNT  65536      // 8*4 = 32
#define ZR_BYTES  65568      // zeroes H1 + CCNT
#define OFF_SEL   65568      // 8*16 = 128 (16B aligned)
#define OFF_BOX   65696      // 8*2000*16 = 256000 (16B aligned)
#define OFF_VALID 321696     // 8*2000*4 = 64000
#define OFF_SUP   385696     // 8*2000*32*8 = 4096000 (16B aligned)
#define OFF_CAND  385696     // overlay on sup (lifetime: gather->rank; sup written after by supmat)
#define OFF_SUPT  4481696    // transposed 64x64 diag blocks: 8*32*64*8 = 131072

// NOTE (r5 lesson): NO device-scope fences/atomic spins anywhere — agent-scope
// release/acquire on multi-XCD gfx950 costs ~100 µs at 256-block scale
// (measured k_front 160 µs vs ~25 µs of real work). Kernel boundaries are the
// only cross-block sync.

__device__ __forceinline__ unsigned int xform(float f) {
    unsigned int b = __float_as_uint(f);
    return b ^ ((unsigned int)((int)b >> 31) | 0x80000000u);  // monotonic float->uint
}

// LDS-only barrier: does NOT drain vmcnt, so prefetched global loads (private
// VGPR dests) stay in flight across it. LDS ordering via lgkmcnt(0).
__device__ __forceinline__ void bar_lds() {
    asm volatile("s_waitcnt lgkmcnt(0)" ::: "memory");
    __builtin_amdgcn_s_barrier();
}

// ---------------- Kernel A: per-batch 2048-bin hist of top-11 key bits ----------------
__global__ __launch_bounds__(256) void k_hist1(const float* __restrict__ cls,
                                               unsigned int* __restrict__ hist1) {
    int b = blockIdx.y, part = blockIdx.x, tid = threadIdx.x;
    __shared__ unsigned int h[2048];
    for (int i = tid; i < 2048; i += 256) h[i] = 0u;
    __syncthreads();
    const float4* base4 = (const float4*)(cls + (size_t)b * NTOT);
    const int n4 = NTOT / 4;
    int per = (n4 + GSPLIT - 1) / GSPLIT;
    int lo = part * per, hi = lo + per;
    if (hi > n4) hi = n4;
    for (int i = lo + tid; i < hi; i += 256) {
        float4 v = base4[i];
        atomicAdd(&h[xform(v.x) >> 21], 1u);
        atomicAdd(&h[xform(v.y) >> 21], 1u);
        atomicAdd(&h[xform(v.z) >> 21], 1u);
        atomicAdd(&h[xform(v.w) >> 21], 1u);
    }
    __syncthreads();
    unsigned int* gh = hist1 + b * 2048;
    for (int i = tid; i < 2048; i += 256)
        if (h[i]) atomicAdd(&gh[i], h[i]);
}

// ---------------- Kernel B: suffix-scan hist1, find threshold bin ----------------
__global__ __launch_bounds__(1024) void k_scan1(const unsigned int* __restrict__ hist1,
                                                uint4* __restrict__ selinfo) {
    int b = blockIdx.x, tid = threadIdx.x;
    __shared__ unsigned int sa[2048], sb[2048];
    const unsigned int* h = hist1 + b * 2048;
    sa[tid] = h[tid];
    sa[tid + 1024] = h[tid + 1024];
    unsigned int* src = sa; unsigned int* dst = sb;
    for (int d = 1; d < 2048; d <<= 1) {
        __syncthreads();
        dst[tid] = src[tid] + ((tid + d < 2048) ? src[tid + d] : 0u);
        int i2 = tid + 1024;
        dst[i2] = src[i2] + ((i2 + d < 2048) ? src[i2 + d] : 0u);
        unsigned int* t = src; src = dst; dst = t;
    }
    __syncthreads();
    #pragma unroll
    for (int k = 0; k < 2; ++k) {
        int i = tid + k * 1024;
        unsigned int c = src[i];
        unsigned int cn = (i < 2047) ? src[i + 1] : 0u;
        if (c >= KSEL && cn < KSEL)
            selinfo[b] = make_uint4((unsigned int)i, cn, KSEL - cn, 0u);
    }
}

// -------- Kernel C: gather all keys with bin >= threshold bin (block-local compaction) --------
__global__ __launch_bounds__(256) void k_gather(const float* __restrict__ cls,
                                                const uint4* __restrict__ selinfo,
                                                unsigned long long* __restrict__ cand,
                                                unsigned int* __restrict__ ccnt) {
    int b = blockIdx.y, part = blockIdx.x, tid = threadIdx.x;
    unsigned int bin = selinfo[b].x;
    __shared__ unsigned long long lbuf[1024];
    __shared__ unsigned int lcnt, gbase;
    if (tid == 0) lcnt = 0u;
    __syncthreads();
    const float4* base4 = (const float4*)(cls + (size_t)b * NTOT);
    const int n4 = NTOT / 4;
    int per = (n4 + GSPLIT - 1) / GSPLIT;
    int lo = part * per, hi = lo + per;
    if (hi > n4) hi = n4;
    for (int i = lo + tid; i < hi; i += 256) {
        float4 v = base4[i];
        float vals[4] = {v.x, v.y, v.z, v.w};
        int idx0 = i * 4;
        #pragma unroll
        for (int q = 0; q < 4; ++q) {
            unsigned int u = xform(vals[q]);
            if ((u >> 21) >= bin) {
                int idx = idx0 + q;
                int a = idx / HWSZ;
                int hw = idx - a * HWSZ;
                unsigned int n = (unsigned int)(hw * NA + a);
                unsigned int pos = atomicAdd(&lcnt, 1u);
                if (pos < 1024u)
                    lbuf[pos] = ((unsigned long long)u << 32) | (unsigned long long)(~n);
            }
        }
    }
    __syncthreads();
    if (tid == 0) {
        unsigned int c = lcnt < 1024u ? lcnt : 1024u;
        gbase = atomicAdd(&ccnt[b], c);
    }
    __syncthreads();
    unsigned int c = lcnt < 1024u ? lcnt : 1024u;
    unsigned int gb = gbase;
    for (unsigned int i = tid; i < c; i += 256) {
        unsigned int p = gb + i;
        if (p < CANDCAP) cand[(size_t)b * CANDCAP + p] = lbuf[i];
    }
}

// -------- Kernel E: rank-by-count (4 threads/key) directly on candidates + box decode --------
__global__ __launch_bounds__(256) void k_rank_decode(
        const unsigned long long* __restrict__ cand,
        const unsigned int* __restrict__ ccnt,
        const float* __restrict__ regs,
        const float* __restrict__ anchors,
        const int* __restrict__ img_h,
        const int* __restrict__ img_w,
        float* __restrict__ out_scores,
        float4* __restrict__ boxes_ws,
        unsigned int* __restrict__ valid_ws) {
    int b = blockIdx.y;
    int tid = threadIdx.x;
    unsigned int sc = ccnt[b];
    if (sc > CANDCAP) sc = CANDCAP;
    unsigned int kbase = blockIdx.x * 64;
    if (kbase >= sc) return;   // uniform early-out for spare blocks
    int ki = tid & 63;         // key slot within block (== lane)
    int q = tid >> 6;          // column-quarter 0..3 (== wave id)
    int lane = tid & 63;
    const unsigned long long* sb_ = cand + (size_t)b * CANDCAP;
    unsigned int r = kbase + (unsigned int)ki;
    unsigned long long mykey = (r < sc) ? sb_[r] : 0ULL;

    // quarter column range [lo, hi); qs is a multiple of 64 with 4*qs >= sc
    unsigned int qs = ((sc + 255u) >> 8) << 6;
    unsigned int lo = (unsigned int)q * qs;
    unsigned int hi = lo + qs;
    if (hi > sc) hi = sc;

    unsigned int cnt = 0u;
    for (unsigned int base = lo; base < hi; base += 64) {
        unsigned long long kj = 0ULL;   // 0 > mykey is false for any real key
        if (base + (unsigned int)lane < hi) kj = sb_[base + lane];
        unsigned int klo = (unsigned int)kj;
        unsigned int khi = (unsigned int)(kj >> 32);
        #pragma unroll
        for (int t = 0; t < 64; ++t) {
            unsigned int lo_ = (unsigned int)__builtin_amdgcn_readlane((int)klo, t);
            unsigned int hi_ = (unsigned int)__builtin_amdgcn_readlane((int)khi, t);
            unsigned long long kt = ((unsigned long long)hi_ << 32) | (unsigned long long)lo_;
            cnt += (kt > mykey) ? 1u : 0u;
        }
    }
    __shared__ unsigned int cntsh[4][64];
    cntsh[q][ki] = cnt;
    __syncthreads();
    if (tid >= 64) return;
    unsigned int rank = cntsh[0][ki] + cntsh[1][ki] + cntsh[2][ki] + cntsh[3][ki];
    if (r >= sc || rank >= KSEL) return;

    int hv = img_h[0];
    int wv = img_w[0];
    float himg = (hv > 0 && hv < 100000) ? (float)hv : __int_as_float(hv);
    float wimg = (wv > 0 && wv < 100000) ? (float)wv : __int_as_float(wv);

    unsigned int u = (unsigned int)(mykey >> 32);
    unsigned int n = ~((unsigned int)mykey);
    unsigned int bits = (u & 0x80000000u) ? (u & 0x7FFFFFFFu) : ~u;
    float score = __uint_as_float(bits);
    int a = (int)(n % NA);
    int hw = (int)(n / NA);
    const float* rp = regs + ((size_t)b * (4 * NA) + 4 * a) * HWSZ + hw;
    float dx = rp[0 * HWSZ];
    float dy = rp[1 * HWSZ];
    float dh = rp[2 * HWSZ];
    float dw = rp[3 * HWSZ];
    const float* ap = anchors + ((size_t)b * NTOT + n) * 4;
    float ax1 = ap[0], ay1 = ap[1], ax2 = ap[2], ay2 = ap[3];
    float ahh = ay2 - ay1;
    float aww = ax2 - ax1;
    float cx = aww * 0.5f;
    float cy = ahh * 0.5f;
    float px = cx + dx * aww;
    float py = cy + dy * ahh;
    dh = fminf(dh, LOG_MAX_F);
    dw = fminf(dw, LOG_MAX_F);
    float ph = expf(dh) * ahh;
    float pw = expf(dw) * aww;
    float x1 = px - pw * 0.5f;
    float y1 = py - ph * 0.5f;
    float x2 = px + pw * 0.5f;
    float y2 = py + ph * 0.5f;
    float bwv = fminf(fmaxf(x2, 0.f), wimg) - fminf(fmaxf(x1, 0.f), wimg);
    float bhv = fminf(fmaxf(y2, 0.f), himg) - fminf(fmaxf(y1, 0.f), himg);
    unsigned int valid = (bwv >= 16.f && bhv >= 16.f) ? 1u : 0u;
    size_t o = (size_t)b * KSEL + rank;   // output position = rank
    out_scores[o] = score;
    boxes_ws[o] = make_float4(x1, y1, x2, y2);
    valid_ws[o] = valid;
}

// -------- Kernel 3: suppression bitmask matrix (upper triangle) + transposed diag blocks --------
__global__ __launch_bounds__(256) void k_supmat(const float4* __restrict__ boxes_ws,
                                                unsigned long long* __restrict__ sup,
                                                unsigned long long* __restrict__ supT) {
    int ct = blockIdx.x;    // col tile 0..31
    int rt = blockIdx.y;    // row super-tile 0..7 (256 rows each)
    int b  = blockIdx.z;
    // entire tile strictly below diagonal (all j < i): words are never consumed -> skip
    if (ct * 64 + 63 < rt * 256) return;
    int tid = threadIdx.x;
    __shared__ float4 colbox[64];
    int j0 = ct * 64;
    if (tid < 64) {
        int jl = j0 + tid;
        colbox[tid] = (jl < KSEL) ? boxes_ws[(size_t)b * KSEL + jl]
                                  : make_float4(0.f, 0.f, 0.f, 0.f);
    }
    __syncthreads();
    int i = rt * 256 + tid;
    if (i >= KSEL) return;
    float4 bi = boxes_ws[(size_t)b * KSEL + i];
    float area_i = (bi.z - bi.x) * (bi.w - bi.y);
    unsigned long long word = 0ULL;
    #pragma unroll 8
    for (int jj = 0; jj < 64; ++jj) {
        int j = j0 + jj;
        float4 bj = colbox[jj];
        float area_j = (bj.z - bj.x) * (bj.w - bj.y);
        float ix1 = fmaxf(bi.x, bj.x);
        float iy1 = fmaxf(bi.y, bj.y);
        float ix2 = fminf(bi.z, bj.z);
        float iy2 = fminf(bi.w, bj.w);
        float iw = fmaxf(ix2 - ix1, 0.f);
        float ih = fmaxf(iy2 - iy1, 0.f);
        float inter = iw * ih;
        float uni = area_i + area_j - inter;
        float iou = inter / fmaxf(uni, 1e-6f);
        bool s = (j > i) && (j < KSEL) && (iou > 0.7f);
        if (s) word |= (1ULL << jj);
    }
    // store only words on/above the row's diagonal tile — lower-triangle words
    // are never read by k_nms_scan (saves ~half the write traffic)
    if (ct >= (i >> 6))
        sup[((size_t)b * KSEL + i) * 32 + ct] = word;

    // diagonal wave: emit transposed 64x64 block (column masks) for the NMS fixpoint.
    // wave-uniform condition: wave q covers rows rt*256+q*64..+63 == cols of tile ct.
    if (ct == rt * 4 + (tid >> 6)) {
        int lane = tid & 63;
        unsigned long long cm = 0ULL;
        #pragma unroll
        for (int j = 0; j < 64; ++j) {
            unsigned long long t = __ballot((word >> j) & 1ULL);
            if (lane == j) cm = t;
        }
        supT[((size_t)b * 32 + ct) * 64 + lane] = cm;
    }
}

// ---- Kernel 4: word-tile greedy scan — transposed-diag Jacobi fixpoint, lazy accw,
//      depth-4 prefetch with UNCONDITIONAL clamped loads (no select on load results:
//      the vmcnt wait stays at first USE, so loads genuinely overlap processing) ----
// Per-thread invariant: thread holds word-pair {2p, 2p+1}, p = tid&15, for rows
// lr = (tid>>4) + k*16, k=0..3.
//   - rows >= KSEL: clamped to row 1999; garbage never consumed (kws masks bits >= 2000)
//   - dead pairs (2p+1 < w, lower triangle): remapped to pair 15 (valid address,
//     coalesces with live readers); garbage never applied (both wd guards fail)
#define LOAD_TILE(wnext, buf)                                                \
    {                                                                        \
        int w_ = (wnext);                                                    \
        _Pragma("unroll")                                                    \
        for (int k = 0; k < 4; ++k) {                                        \
            int lr_ = (tid >> 4) + k * 16;                                   \
            int grow_ = w_ * 64 + lr_;                                       \
            if (grow_ > KSEL - 1) grow_ = KSEL - 1;                          \
            int pp_ = (2 * p + 1 >= w_) ? p : 15;                            \
            buf[k] = srowp[(size_t)grow_ * 16 + pp_];                        \
        }                                                                    \
    }

// One LDS barrier per tile (accw visibility). In-tile suppression solved by
// Jacobi fixpoint on the transposed diag block:
//   keep = cand & ~(sup^T . keep)  — antitone on a strictly-triangular DAG
// => unique fixpoint == exact sequential greedy.
#define PROCESS_TILE(w, buf)                                                 \
    {                                                                        \
        bar_lds();                                                           \
        int w_ = (w);                                                        \
        unsigned long long pend_ =                                           \
            ((unsigned long long)accw[w_ * 2 + 1] << 32)                     \
            | (unsigned long long)accw[w_ * 2];                              \
        unsigned long long cand_ = kws[w_] & ~pend_;                         \
        unsigned int clo_ = __builtin_amdgcn_readfirstlane((unsigned int)cand_);        \
        unsigned int chi_ = __builtin_amdgcn_readfirstlane((unsigned int)(cand_ >> 32));\
        unsigned long long cur_ = ((unsigned long long)chi_ << 32)           \
                                  | (unsigned long long)clo_;                \
        if (cur_) {                                                          \
            unsigned long long cmw_ = colT[w_ * 64 + lane];                  \
            unsigned long long k_ = cur_;                                    \
            for (;;) {                                                       \
                unsigned long long sup_ = __ballot((k_ & cmw_) != 0ULL);     \
                unsigned long long k2_ = cur_ & ~sup_;                       \
                if (k2_ == k_) break;                                        \
                k_ = k2_;                                                    \
            }                                                                \
            cur_ = k_;                                                       \
            if (tid == 0) fin[w_] = cur_;                                    \
            unsigned long long v0_ = 0ULL, v1_ = 0ULL;                       \
            _Pragma("unroll")                                                \
            for (int k = 0; k < 4; ++k) {                                    \
                int lr_ = (tid >> 4) + k * 16;                               \
                if ((cur_ >> lr_) & 1ULL) { v0_ |= buf[k].x; v1_ |= buf[k].y; } \
            }                                                                \
            v0_ |= __shfl_xor(v0_, 16, 64); v0_ |= __shfl_xor(v0_, 32, 64);  \
            v1_ |= __shfl_xor(v1_, 16, 64); v1_ |= __shfl_xor(v1_, 32, 64);  \
            if (lane < 16) {                                                 \
                int wd0_ = 2 * p;                                            \
                if (wd0_ > w_ && v0_) {                                      \
                    atomicOr(&accw[wd0_ * 2], (unsigned int)v0_);            \
                    atomicOr(&accw[wd0_ * 2 + 1], (unsigned int)(v0_ >> 32));\
                }                                                            \
                if (wd0_ + 1 > w_ && v1_) {                                  \
                    atomicOr(&accw[wd0_ * 2 + 2], (unsigned int)v1_);        \
                    atomicOr(&accw[wd0_ * 2 + 3], (unsigned int)(v1_ >> 32));\
                }                                                            \
            }                                                                \
        } else if (tid == 0) {                                               \
            fin[w_] = 0ULL;                                                  \
        }                                                                    \
    }

__global__ __launch_bounds__(256) void k_nms_scan(const unsigned long long* __restrict__ sup,
                                                  const unsigned long long* __restrict__ supT,
                                                  const unsigned int* __restrict__ valid_ws,
                                                  const float4* __restrict__ boxes_ws,
                                                  float* __restrict__ out_boxes,
                                                  float* __restrict__ out_keep) {
    int b = blockIdx.x;
    int tid = threadIdx.x;
    int lane = tid & 63;
    int p = tid & 15;                            // word-pair index
    __shared__ unsigned long long kws[32];       // initial validity words
    __shared__ unsigned long long fin[32];       // final keep words
    __shared__ unsigned int accw[64];            // lazy suppression accumulator (monotone)
    __shared__ unsigned long long colT[32 * 64]; // transposed diag blocks (16 KB)
    const ulonglong2* srowp = (const ulonglong2*)(sup + (size_t)b * KSEL * 32);

    // preload all transposed diag columns (read-only afterwards)
    {
        const unsigned long long* stb = supT + (size_t)b * 2048;
        #pragma unroll
        for (int k = 0; k < 8; ++k) {
            int i = tid + k * 256;
            colT[i] = stb[i];
        }
    }

    if (tid < 32) {
        unsigned long long kw = 0ULL;
        const uint4* vv = (const uint4*)(valid_ws + (size_t)b * KSEL);
        #pragma unroll 4
        for (int q = 0; q < 16; ++q) {
            uint4 x = vv[tid * 16 + q];   // tid=31,q>=4 reads past 2000 — bits masked below
            int base = q * 4;
            if (x.x) kw |= 1ULL << (base + 0);
            if (x.y) kw |= 1ULL << (base + 1);
            if (x.z) kw |= 1ULL << (base + 2);
            if (x.w) kw |= 1ULL << (base + 3);
        }
        if (tid == 31) kw &= 0xFFFFULL;   // rows 2000..2047 invalid
        kws[tid] = kw;
    }
    if (tid < 64) accw[tid] = 0u;

    // depth-4 prefetch rotation: cover ~3 process-steps of latency
    ulonglong2 A[4], B[4], C[4], D[4];
    LOAD_TILE(0, A);
    LOAD_TILE(1, B);
    LOAD_TILE(2, C);
    LOAD_TILE(3, D);

    for (int t = 0; t < 8; ++t) {
        int w = 4 * t;
        PROCESS_TILE(w, A);
        if (w + 4 < 32) LOAD_TILE(w + 4, A);   // stays in flight across bar_lds
        PROCESS_TILE(w + 1, B);
        if (w + 5 < 32) LOAD_TILE(w + 5, B);
        PROCESS_TILE(w + 2, C);
        if (w + 6 < 32) LOAD_TILE(w + 6, C);
        PROCESS_TILE(w + 3, D);
        if (w + 7 < 32) LOAD_TILE(w + 7, D);
    }
    bar_lds();

    float4* ob4 = (float4*)out_boxes;
    for (int r = tid; r < KSEL; r += 256) {
        float kf = (float)((fin[r >> 6] >> (r & 63)) & 1ULL);
        size_t o = (size_t)b * KSEL + r;
        out_keep[o] = kf;
        float4 bx = boxes_ws[o];
        ob4[o] = make_float4(bx.x * kf, bx.y * kf, bx.z * kf, bx.w * kf);
    }
}

extern "C" void kernel_launch(void* const* d_in, const int* in_sizes, int n_in,
                              void* d_out, int out_size, void* d_ws, size_t ws_size,
                              hipStream_t stream) {
    const float* cls     = (const float*)d_in[0];
    const float* regs    = (const float*)d_in[1];
    const float* anchors = (const float*)d_in[2];
    const int*   img_h   = (const int*)d_in[3];
    const int*   img_w   = (const int*)d_in[4];

    float* out = (float*)d_out;
    float* out_boxes  = out;            // 8*2000*4
    float* out_scores = out + 64000;    // 8*2000
    float* out_keep   = out + 80000;    // 8*2000

    char* ws = (char*)d_ws;
    unsigned int* hist1      = (unsigned int*)(ws + OFF_H1);
    unsigned int* ccnt       = (unsigned int*)(ws + OFF_CCNT);
    uint4* selinfo           = (uint4*)(ws + OFF_SEL);
    float4* boxes_ws         = (float4*)(ws + OFF_BOX);
    unsigned int* valid_ws   = (unsigned int*)(ws + OFF_VALID);
    unsigned long long* sup  = (unsigned long long*)(ws + OFF_SUP);
    unsigned long long* cand = (unsigned long long*)(ws + OFF_CAND);
    unsigned long long* supT = (unsigned long long*)(ws + OFF_SUPT);

    hipMemsetAsync(ws, 0, ZR_BYTES, stream);
    k_hist1<<<dim3(GSPLIT, NBATCH), 256, 0, stream>>>(cls, hist1);
    k_scan1<<<NBATCH, 1024, 0, stream>>>(hist1, selinfo);
    k_gather<<<dim3(GSPLIT, NBATCH), 256, 0, stream>>>(cls, selinfo, cand, ccnt);
    k_rank_decode<<<dim3(CANDCAP / 64, NBATCH), 256, 0, stream>>>(cand, ccnt, regs, anchors,
                                                                  img_h, img_w, out_scores,
                                                                  boxes_ws, valid_ws);
    k_supmat<<<dim3(32, 8, NBATCH), 256, 0, stream>>>(boxes_ws, sup, supT);
    k_nms_scan<<<NBATCH, 256, 0, stream>>>(sup, supT, valid_ws, boxes_ws, out_boxes, out_keep);
}